// Round 1
// baseline (499.087 us; speedup 1.0000x reference)
//
#include <hip/hip_runtime.h>
#include <hip/hip_bf16.h>
#include <math.h>

#define B_N   2000
#define T_N   32
#define CIN_N 32
#define COUT_N 128
#define E_N   32000
#define NEG_S 0.01f
#define EPS_S 1e-5f
#define NNODE (B_N * T_N)   // 64000

// ---------------- Kernel 1: causal conv1d + bias + LeakyReLU + LayerNorm ----------------
// One block per batch sample b. Writes xp[(t*B+b)*128 + co] (node-major layout).
__global__ __launch_bounds__(256) void k_conv_ln(
    const float* __restrict__ x, const float* __restrict__ cw,
    const float* __restrict__ cb, const float* __restrict__ gamma,
    const float* __restrict__ beta, float* __restrict__ xp)
{
  __shared__ float sw[128 * 97];   // conv_w, padded row stride 97 (96 used) -> conflict-free
  __shared__ float sx[32 * 34];    // x[b] with 2-left zero pad per channel row
  __shared__ float red1[4], red2[4], sstat[2];
  const int b = blockIdx.x;
  const int tid = threadIdx.x;

  for (int idx = tid; idx < 128 * 96; idx += 256) {
    int co = idx / 96, r = idx - co * 96;
    sw[co * 97 + r] = cw[idx];
  }
  for (int idx = tid; idx < 32 * 34; idx += 256) {
    int ci = idx / 34, tt = idx - ci * 34;
    sx[idx] = (tt < 2) ? 0.f : x[b * 1024 + ci * 32 + (tt - 2)];
  }
  __syncthreads();

  float yv[16];
  float s1 = 0.f, s2 = 0.f;
  #pragma unroll
  for (int i = 0; i < 16; ++i) {
    int idx = i * 256 + tid;
    int t = idx >> 7, co = idx & 127;
    float acc = cb[co];
    const float* wr = &sw[co * 97];
    const float* xr = &sx[t];
    #pragma unroll
    for (int ci = 0; ci < 32; ++ci) {
      acc += xr[ci * 34 + 0] * wr[ci * 3 + 0];
      acc += xr[ci * 34 + 1] * wr[ci * 3 + 1];
      acc += xr[ci * 34 + 2] * wr[ci * 3 + 2];
    }
    acc = (acc >= 0.f) ? acc : NEG_S * acc;   // LeakyReLU before LN (matches reference)
    yv[i] = acc;
    s1 += acc; s2 += acc * acc;
  }

  // block reduction for mean/var over 4096 elements
  int lane = tid & 63, wid = tid >> 6;
  #pragma unroll
  for (int d = 32; d > 0; d >>= 1) {
    s1 += __shfl_down(s1, d);
    s2 += __shfl_down(s2, d);
  }
  if (lane == 0) { red1[wid] = s1; red2[wid] = s2; }
  __syncthreads();
  if (tid == 0) {
    float a = red1[0] + red1[1] + red1[2] + red1[3];
    float c = red2[0] + red2[1] + red2[2] + red2[3];
    float mu = a / 4096.f;
    float var = c / 4096.f - mu * mu;
    sstat[0] = mu;
    sstat[1] = rsqrtf(var + EPS_S);
  }
  __syncthreads();
  const float mu = sstat[0], rs = sstat[1];

  #pragma unroll
  for (int i = 0; i < 16; ++i) {
    int idx = i * 256 + tid;
    int t = idx >> 7, co = idx & 127;
    float g  = gamma[co * 32 + t];
    float bb = beta[co * 32 + t];
    xp[(size_t)(t * B_N + b) * 128 + co] = (yv[i] - mu) * rs * g + bb;
  }
}

// ---------------- Kernel 2: in-degree (weighted) + in-edge counts ----------------
__global__ void k_deg(const int* __restrict__ ei, const float* __restrict__ ew,
                      float* __restrict__ deg, int* __restrict__ cnt)
{
  int e = blockIdx.x * 256 + threadIdx.x;
  if (e >= E_N) return;
  int d = ei[E_N + e];
  atomicAdd(&deg[d], ew[e]);
  atomicAdd(&cnt[d], 1);
}

// ---------------- Kernel 3: single-block exclusive scan over 2000 counts ----------------
__global__ __launch_bounds__(256) void k_scan(const int* __restrict__ cnt, int* __restrict__ offs)
{
  __shared__ int wsum[4];
  int tid = threadIdx.x;
  int vals[8];
  int run = 0;
  #pragma unroll
  for (int i = 0; i < 8; ++i) {
    int idx = tid * 8 + i;
    vals[i] = run;
    int v = (idx < B_N) ? cnt[idx] : 0;
    run += v;
  }
  int lane = tid & 63, wid = tid >> 6;
  int xs = run;
  #pragma unroll
  for (int d = 1; d < 64; d <<= 1) {
    int y = __shfl_up(xs, d);
    if (lane >= d) xs += y;
  }
  if (lane == 63) wsum[wid] = xs;
  __syncthreads();
  int pre = 0;
  for (int w = 0; w < wid; ++w) pre += wsum[w];
  int excl = pre + xs - run;   // exclusive prefix for this thread's first element
  #pragma unroll
  for (int i = 0; i < 8; ++i) {
    int idx = tid * 8 + i;
    if (idx <= B_N) offs[idx] = excl + vals[i];
  }
}

// ---------------- Kernel 4: CSR scatter + edge norm ----------------
__global__ void k_scatter(const int* __restrict__ ei, const float* __restrict__ ew,
                          const float* __restrict__ deg, const int* __restrict__ offs,
                          int* __restrict__ cursor, int* __restrict__ csr_src,
                          float* __restrict__ csr_norm)
{
  int e = blockIdx.x * 256 + threadIdx.x;
  if (e >= E_N) return;
  int s = ei[e], d = ei[E_N + e];
  float ds_ = deg[s], dd = deg[d];
  float dis_s = (ds_ > 0.f) ? rsqrtf(fmaxf(ds_, 1e-12f)) : 0.f;
  float dis_d = (dd  > 0.f) ? rsqrtf(fmaxf(dd,  1e-12f)) : 0.f;
  float nrm = dis_s * ew[e] * dis_d;
  int pos = offs[d] + atomicAdd(&cursor[d], 1);
  csr_src[pos] = s;
  csr_norm[pos] = nrm;
}

// ---------------- Kernel 5: one-hop propagation, 1 wave per (dst node, timestep) ----------------
__global__ __launch_bounds__(256) void k_prop(
    const float* __restrict__ hin, float* __restrict__ hout,
    const int* __restrict__ offs, const int* __restrict__ csr_src,
    const float* __restrict__ csr_norm)
{
  int gw = (blockIdx.x * 256 + threadIdx.x) >> 6;  // global wave id == node id (t*B+b)
  int lane = threadIdx.x & 63;
  if (gw >= NNODE) return;
  int t = gw / B_N;
  int b = gw - t * B_N;
  int beg = offs[b], end = offs[b + 1];
  const float* base = hin + (size_t)t * B_N * 128;
  int c = lane * 2;
  float2 acc = make_float2(0.f, 0.f);
  for (int i = beg; i < end; ++i) {
    int s = csr_src[i];
    float nm = csr_norm[i];
    float2 v = *(const float2*)(base + (size_t)s * 128 + c);
    acc.x += nm * v.x;
    acc.y += nm * v.y;
  }
  *(float2*)(hout + (size_t)gw * 128 + c) = acc;
}

// ---------------- Kernel 6: fused triple GEMM + bias + LeakyReLU + residual ----------------
// out_row = xp + lrelu(xp@W0 + h1@W1 + h2@W2 + tb); written over h2 (tile fully staged first).
__global__ __launch_bounds__(256) void k_gemm(
    const float* __restrict__ xp, const float* __restrict__ h1,
    float* __restrict__ h2, const float* __restrict__ tw,
    const float* __restrict__ tb)
{
  __shared__ float sX[32 * 128];
  __shared__ float sA[32 * 128];
  __shared__ float sB[32 * 128];
  const int tid = threadIdx.x;
  const int n0 = blockIdx.x * 32;

  const float4* x4 = (const float4*)(xp + (size_t)n0 * 128);
  const float4* a4 = (const float4*)(h1 + (size_t)n0 * 128);
  const float4* b4 = (const float4*)(h2 + (size_t)n0 * 128);
  #pragma unroll
  for (int j = 0; j < 4; ++j) {
    int id = tid + j * 256;
    ((float4*)sX)[id] = x4[id];
    ((float4*)sA)[id] = a4[id];
    ((float4*)sB)[id] = b4[id];
  }
  __syncthreads();

  const int tx = tid & 31, ty = tid >> 5;
  const int c0 = tx * 4;
  const int r0 = ty * 4;
  float acc[4][4] = {};

  const float* w0 = tw;
  const float* w1 = tw + 16384;
  const float* w2 = tw + 32768;

  for (int k4 = 0; k4 < 32; ++k4) {
    float4 xr[4], ar[4], br[4];
    #pragma unroll
    for (int i = 0; i < 4; ++i) {
      xr[i] = *(const float4*)&sX[(r0 + i) * 128 + k4 * 4];
      ar[i] = *(const float4*)&sA[(r0 + i) * 128 + k4 * 4];
      br[i] = *(const float4*)&sB[(r0 + i) * 128 + k4 * 4];
    }
    #pragma unroll
    for (int kk = 0; kk < 4; ++kk) {
      int k = k4 * 4 + kk;
      float4 wa = *(const float4*)(w0 + (size_t)k * 128 + c0);
      float4 wb = *(const float4*)(w1 + (size_t)k * 128 + c0);
      float4 wc = *(const float4*)(w2 + (size_t)k * 128 + c0);
      #pragma unroll
      for (int i = 0; i < 4; ++i) {
        float xv = ((const float*)&xr[i])[kk];
        float av = ((const float*)&ar[i])[kk];
        float bv = ((const float*)&br[i])[kk];
        acc[i][0] += xv * wa.x + av * wb.x + bv * wc.x;
        acc[i][1] += xv * wa.y + av * wb.y + bv * wc.y;
        acc[i][2] += xv * wa.z + av * wb.z + bv * wc.z;
        acc[i][3] += xv * wa.w + av * wb.w + bv * wc.w;
      }
    }
  }

  const float4 tbv = *(const float4*)(tb + c0);
  #pragma unroll
  for (int i = 0; i < 4; ++i) {
    float4 o;
    float u;
    u = acc[i][0] + tbv.x; u = (u >= 0.f) ? u : NEG_S * u; o.x = sX[(r0 + i) * 128 + c0 + 0] + u;
    u = acc[i][1] + tbv.y; u = (u >= 0.f) ? u : NEG_S * u; o.y = sX[(r0 + i) * 128 + c0 + 1] + u;
    u = acc[i][2] + tbv.z; u = (u >= 0.f) ? u : NEG_S * u; o.z = sX[(r0 + i) * 128 + c0 + 2] + u;
    u = acc[i][3] + tbv.w; u = (u >= 0.f) ? u : NEG_S * u; o.w = sX[(r0 + i) * 128 + c0 + 3] + u;
    *(float4*)(h2 + (size_t)(n0 + r0 + i) * 128 + c0) = o;
  }
}

// ---------------- Kernel 7: transpose [t*B+b][c] -> [b][c][t] ----------------
__global__ __launch_bounds__(256) void k_out(const float* __restrict__ hfin, float* __restrict__ out)
{
  __shared__ float lds[32 * 129];
  const int b = blockIdx.x, tid = threadIdx.x;
  #pragma unroll
  for (int i = 0; i < 16; ++i) {
    int idx = i * 256 + tid;
    int t = idx >> 7, c = idx & 127;
    lds[t * 129 + c] = hfin[(size_t)(t * B_N + b) * 128 + c];
  }
  __syncthreads();
  #pragma unroll
  for (int i = 0; i < 16; ++i) {
    int idx = i * 256 + tid;
    int c = idx >> 5, t = idx & 31;
    out[(size_t)b * 4096 + c * 32 + t] = lds[t * 129 + c];
  }
}

extern "C" void kernel_launch(void* const* d_in, const int* in_sizes, int n_in,
                              void* d_out, int out_size, void* d_ws, size_t ws_size,
                              hipStream_t stream)
{
  const float* x     = (const float*)d_in[0];
  const int*   ei    = (const int*)d_in[1];
  const float* ew    = (const float*)d_in[2];
  const float* cw    = (const float*)d_in[3];
  const float* cb    = (const float*)d_in[4];
  const float* gamma = (const float*)d_in[5];
  const float* beta  = (const float*)d_in[6];
  const float* tw    = (const float*)d_in[7];
  const float* tb    = (const float*)d_in[8];
  float* out = (float*)d_out;

  // workspace layout (floats/ints, 4B units)
  float* xp  = (float*)d_ws;                       // 64000*128
  float* h1  = xp + (size_t)NNODE * 128;           // 64000*128
  float* h2  = h1 + (size_t)NNODE * 128;           // 64000*128
  float* deg = h2 + (size_t)NNODE * 128;           // 2000
  int*   cnt    = (int*)(deg + B_N);               // 2000
  int*   cursor = cnt + B_N;                       // 2000
  int*   offs   = cursor + B_N;                    // 2001
  int*   csr_src = offs + (B_N + 1);               // 32000
  float* csr_norm = (float*)(csr_src + E_N);       // 32000

  // zero deg + cnt + cursor (contiguous 3*2000*4 bytes)
  hipMemsetAsync(deg, 0, (size_t)3 * B_N * 4, stream);

  k_conv_ln<<<B_N, 256, 0, stream>>>(x, cw, cb, gamma, beta, xp);
  k_deg<<<(E_N + 255) / 256, 256, 0, stream>>>(ei, ew, deg, cnt);
  k_scan<<<1, 256, 0, stream>>>(cnt, offs);
  k_scatter<<<(E_N + 255) / 256, 256, 0, stream>>>(ei, ew, deg, offs, cursor, csr_src, csr_norm);
  k_prop<<<NNODE / 4, 256, 0, stream>>>(xp, h1, offs, csr_src, csr_norm);
  k_prop<<<NNODE / 4, 256, 0, stream>>>(h1, h2, offs, csr_src, csr_norm);
  k_gemm<<<NNODE / 32, 256, 0, stream>>>(xp, h1, h2, tw, tb);
  k_out<<<B_N, 256, 0, stream>>>(h2, out);
}

// Round 2
// 384.866 us; speedup vs baseline: 1.2968x; 1.2968x over previous
//
#include <hip/hip_runtime.h>
#include <hip/hip_bf16.h>
#include <math.h>

#define B_N   2000
#define T_N   32
#define CIN_N 32
#define COUT_N 128
#define E_N   32000
#define NEG_S 0.01f
#define EPS_S 1e-5f
#define NNODE (B_N * T_N)   // 64000

// ---------------- Kernel 0: transpose conv weights [128][96] -> [96][128] ----------------
__global__ void k_wt(const float* __restrict__ cw, float* __restrict__ wT)
{
  int idx = blockIdx.x * 256 + threadIdx.x;   // 12288 total
  if (idx >= 96 * 128) return;
  int co = idx / 96, k = idx - co * 96;
  wT[k * 128 + co] = cw[idx];
}

// ---------------- Kernel 1: causal conv1d (as GEMM) + bias + LeakyReLU + LayerNorm ----------------
// One block per batch sample b. 32 t-rows x 128 co-cols output, K=96 (ci*3+kk).
// Register 4x4 tile per thread; 2 ds_read_b128 per k-step for 16 FMAs.
__global__ __launch_bounds__(256) void k_conv_ln(
    const float* __restrict__ x, const float* __restrict__ wT,
    const float* __restrict__ cb, const float* __restrict__ gamma,
    const float* __restrict__ beta, float* __restrict__ xp)
{
  __shared__ float swT[96 * 128];   // [k][co] - contiguous, conflict-free float4 stage
  __shared__ float sxi[96 * 36];    // im2col [k][t], row stride 36 (16B-aligned float4 reads)
  __shared__ float red1[4], red2[4], sstat[2];
  const int b = blockIdx.x;
  const int tid = threadIdx.x;

  // stage transposed weights (coalesced global float4 -> contiguous LDS float4)
  #pragma unroll
  for (int i = 0; i < 12; ++i) {
    int idx = i * 256 + tid;                 // 3072 float4
    ((float4*)swT)[idx] = ((const float4*)wT)[idx];
  }
  // build im2col: sxi[k][t] = x[b, ci, t-2+kk] (zero-pad left), k = ci*3+kk
  #pragma unroll
  for (int i = 0; i < 12; ++i) {
    int idx = i * 256 + tid;                 // 3072 = 96*32
    int k = idx >> 5, t = idx & 31;
    int ci = k / 3, kk = k - ci * 3;
    int tt = t - 2 + kk;
    sxi[k * 36 + t] = (tt >= 0) ? x[b * 1024 + ci * 32 + tt] : 0.f;
  }
  __syncthreads();

  const int tx = tid & 31, ty = tid >> 5;
  const int co0 = tx * 4;                    // 4 consecutive output channels
  const int t0 = ty * 4;                     // 4 consecutive timesteps
  float acc[4][4] = {};

  #pragma unroll 4
  for (int k = 0; k < 96; ++k) {
    const float4 xv = *(const float4*)&sxi[k * 36 + t0];    // broadcast within wave
    const float4 wv = *(const float4*)&swT[k * 128 + co0];  // contiguous across tx
    const float xs[4] = {xv.x, xv.y, xv.z, xv.w};
    #pragma unroll
    for (int i = 0; i < 4; ++i) {
      acc[i][0] += xs[i] * wv.x;
      acc[i][1] += xs[i] * wv.y;
      acc[i][2] += xs[i] * wv.z;
      acc[i][3] += xs[i] * wv.w;
    }
  }

  // bias + LeakyReLU, accumulate LN stats
  const float4 bv = *(const float4*)&cb[co0];
  const float bs[4] = {bv.x, bv.y, bv.z, bv.w};
  float s1 = 0.f, s2 = 0.f;
  #pragma unroll
  for (int i = 0; i < 4; ++i)
    #pragma unroll
    for (int j = 0; j < 4; ++j) {
      float u = acc[i][j] + bs[j];
      u = (u >= 0.f) ? u : NEG_S * u;
      acc[i][j] = u;
      s1 += u; s2 += u * u;
    }

  // block reduction for mean/var over 4096 elements
  const int lane = tid & 63, wid = tid >> 6;
  #pragma unroll
  for (int d = 32; d > 0; d >>= 1) {
    s1 += __shfl_down(s1, d);
    s2 += __shfl_down(s2, d);
  }
  if (lane == 0) { red1[wid] = s1; red2[wid] = s2; }
  __syncthreads();
  if (tid == 0) {
    float a = red1[0] + red1[1] + red1[2] + red1[3];
    float c = red2[0] + red2[1] + red2[2] + red2[3];
    float mu = a / 4096.f;
    float var = c / 4096.f - mu * mu;
    sstat[0] = mu;
    sstat[1] = rsqrtf(var + EPS_S);
  }
  __syncthreads();
  const float mu = sstat[0], rs = sstat[1];

  // normalize + affine, write node-major xp[(t*B+b)*128 + co]
  #pragma unroll
  for (int i = 0; i < 4; ++i) {
    const int t = t0 + i;
    float4 o;
    #pragma unroll
    for (int j = 0; j < 4; ++j) {
      float g  = gamma[(co0 + j) * 32 + t];
      float be = beta[(co0 + j) * 32 + t];
      ((float*)&o)[j] = (acc[i][j] - mu) * rs * g + be;
    }
    *(float4*)&xp[(size_t)(t * B_N + b) * 128 + co0] = o;
  }
}

// ---------------- Kernel 2: in-degree (weighted) + in-edge counts ----------------
__global__ void k_deg(const int* __restrict__ ei, const float* __restrict__ ew,
                      float* __restrict__ deg, int* __restrict__ cnt)
{
  int e = blockIdx.x * 256 + threadIdx.x;
  if (e >= E_N) return;
  int d = ei[E_N + e];
  atomicAdd(&deg[d], ew[e]);
  atomicAdd(&cnt[d], 1);
}

// ---------------- Kernel 3: single-block exclusive scan over 2000 counts ----------------
__global__ __launch_bounds__(256) void k_scan(const int* __restrict__ cnt, int* __restrict__ offs)
{
  __shared__ int wsum[4];
  int tid = threadIdx.x;
  int vals[8];
  int run = 0;
  #pragma unroll
  for (int i = 0; i < 8; ++i) {
    int idx = tid * 8 + i;
    vals[i] = run;
    int v = (idx < B_N) ? cnt[idx] : 0;
    run += v;
  }
  int lane = tid & 63, wid = tid >> 6;
  int xs = run;
  #pragma unroll
  for (int d = 1; d < 64; d <<= 1) {
    int y = __shfl_up(xs, d);
    if (lane >= d) xs += y;
  }
  if (lane == 63) wsum[wid] = xs;
  __syncthreads();
  int pre = 0;
  for (int w = 0; w < wid; ++w) pre += wsum[w];
  int excl = pre + xs - run;   // exclusive prefix for this thread's first element
  #pragma unroll
  for (int i = 0; i < 8; ++i) {
    int idx = tid * 8 + i;
    if (idx <= B_N) offs[idx] = excl + vals[i];
  }
}

// ---------------- Kernel 4: CSR scatter + edge norm ----------------
__global__ void k_scatter(const int* __restrict__ ei, const float* __restrict__ ew,
                          const float* __restrict__ deg, const int* __restrict__ offs,
                          int* __restrict__ cursor, int* __restrict__ csr_src,
                          float* __restrict__ csr_norm)
{
  int e = blockIdx.x * 256 + threadIdx.x;
  if (e >= E_N) return;
  int s = ei[e], d = ei[E_N + e];
  float ds_ = deg[s], dd = deg[d];
  float dis_s = (ds_ > 0.f) ? rsqrtf(fmaxf(ds_, 1e-12f)) : 0.f;
  float dis_d = (dd  > 0.f) ? rsqrtf(fmaxf(dd,  1e-12f)) : 0.f;
  float nrm = dis_s * ew[e] * dis_d;
  int pos = offs[d] + atomicAdd(&cursor[d], 1);
  csr_src[pos] = s;
  csr_norm[pos] = nrm;
}

// ---------------- Kernel 5: one-hop propagation, 1 wave per (dst node, timestep) ----------------
__global__ __launch_bounds__(256) void k_prop(
    const float* __restrict__ hin, float* __restrict__ hout,
    const int* __restrict__ offs, const int* __restrict__ csr_src,
    const float* __restrict__ csr_norm)
{
  int gw = (blockIdx.x * 256 + threadIdx.x) >> 6;  // global wave id == node id (t*B+b)
  int lane = threadIdx.x & 63;
  if (gw >= NNODE) return;
  int t = gw / B_N;
  int b = gw - t * B_N;
  int beg = offs[b], end = offs[b + 1];
  const float* base = hin + (size_t)t * B_N * 128;
  int c = lane * 2;
  float2 acc = make_float2(0.f, 0.f);
  for (int i = beg; i < end; ++i) {
    int s = csr_src[i];
    float nm = csr_norm[i];
    float2 v = *(const float2*)(base + (size_t)s * 128 + c);
    acc.x += nm * v.x;
    acc.y += nm * v.y;
  }
  *(float2*)(hout + (size_t)gw * 128 + c) = acc;
}

// ---------------- Kernel 6: fused triple GEMM + bias + LeakyReLU + residual ----------------
// out_row = xp + lrelu(xp@W0 + h1@W1 + h2@W2 + tb); written over h2 (tile fully staged first).
__global__ __launch_bounds__(256) void k_gemm(
    const float* __restrict__ xp, const float* __restrict__ h1,
    float* __restrict__ h2, const float* __restrict__ tw,
    const float* __restrict__ tb)
{
  __shared__ float sX[32 * 128];
  __shared__ float sA[32 * 128];
  __shared__ float sB[32 * 128];
  const int tid = threadIdx.x;
  const int n0 = blockIdx.x * 32;

  const float4* x4 = (const float4*)(xp + (size_t)n0 * 128);
  const float4* a4 = (const float4*)(h1 + (size_t)n0 * 128);
  const float4* b4 = (const float4*)(h2 + (size_t)n0 * 128);
  #pragma unroll
  for (int j = 0; j < 4; ++j) {
    int id = tid + j * 256;
    ((float4*)sX)[id] = x4[id];
    ((float4*)sA)[id] = a4[id];
    ((float4*)sB)[id] = b4[id];
  }
  __syncthreads();

  const int tx = tid & 31, ty = tid >> 5;
  const int c0 = tx * 4;
  const int r0 = ty * 4;
  float acc[4][4] = {};

  const float* w0 = tw;
  const float* w1 = tw + 16384;
  const float* w2 = tw + 32768;

  for (int k4 = 0; k4 < 32; ++k4) {
    float4 xr[4], ar[4], br[4];
    #pragma unroll
    for (int i = 0; i < 4; ++i) {
      xr[i] = *(const float4*)&sX[(r0 + i) * 128 + k4 * 4];
      ar[i] = *(const float4*)&sA[(r0 + i) * 128 + k4 * 4];
      br[i] = *(const float4*)&sB[(r0 + i) * 128 + k4 * 4];
    }
    #pragma unroll
    for (int kk = 0; kk < 4; ++kk) {
      int k = k4 * 4 + kk;
      float4 wa = *(const float4*)(w0 + (size_t)k * 128 + c0);
      float4 wb = *(const float4*)(w1 + (size_t)k * 128 + c0);
      float4 wc = *(const float4*)(w2 + (size_t)k * 128 + c0);
      #pragma unroll
      for (int i = 0; i < 4; ++i) {
        float xv = ((const float*)&xr[i])[kk];
        float av = ((const float*)&ar[i])[kk];
        float bv = ((const float*)&br[i])[kk];
        acc[i][0] += xv * wa.x + av * wb.x + bv * wc.x;
        acc[i][1] += xv * wa.y + av * wb.y + bv * wc.y;
        acc[i][2] += xv * wa.z + av * wb.z + bv * wc.z;
        acc[i][3] += xv * wa.w + av * wb.w + bv * wc.w;
      }
    }
  }

  const float4 tbv = *(const float4*)(tb + c0);
  #pragma unroll
  for (int i = 0; i < 4; ++i) {
    float4 o;
    float u;
    u = acc[i][0] + tbv.x; u = (u >= 0.f) ? u : NEG_S * u; o.x = sX[(r0 + i) * 128 + c0 + 0] + u;
    u = acc[i][1] + tbv.y; u = (u >= 0.f) ? u : NEG_S * u; o.y = sX[(r0 + i) * 128 + c0 + 1] + u;
    u = acc[i][2] + tbv.z; u = (u >= 0.f) ? u : NEG_S * u; o.z = sX[(r0 + i) * 128 + c0 + 2] + u;
    u = acc[i][3] + tbv.w; u = (u >= 0.f) ? u : NEG_S * u; o.w = sX[(r0 + i) * 128 + c0 + 3] + u;
    *(float4*)(h2 + (size_t)(n0 + r0 + i) * 128 + c0) = o;
  }
}

// ---------------- Kernel 7: transpose [t*B+b][c] -> [b][c][t] ----------------
__global__ __launch_bounds__(256) void k_out(const float* __restrict__ hfin, float* __restrict__ out)
{
  __shared__ float lds[32 * 129];
  const int b = blockIdx.x, tid = threadIdx.x;
  #pragma unroll
  for (int i = 0; i < 16; ++i) {
    int idx = i * 256 + tid;
    int t = idx >> 7, c = idx & 127;
    lds[t * 129 + c] = hfin[(size_t)(t * B_N + b) * 128 + c];
  }
  __syncthreads();
  #pragma unroll
  for (int i = 0; i < 16; ++i) {
    int idx = i * 256 + tid;
    int c = idx >> 5, t = idx & 31;
    out[(size_t)b * 4096 + c * 32 + t] = lds[t * 129 + c];
  }
}

extern "C" void kernel_launch(void* const* d_in, const int* in_sizes, int n_in,
                              void* d_out, int out_size, void* d_ws, size_t ws_size,
                              hipStream_t stream)
{
  const float* x     = (const float*)d_in[0];
  const int*   ei    = (const int*)d_in[1];
  const float* ew    = (const float*)d_in[2];
  const float* cw    = (const float*)d_in[3];
  const float* cb    = (const float*)d_in[4];
  const float* gamma = (const float*)d_in[5];
  const float* beta  = (const float*)d_in[6];
  const float* tw    = (const float*)d_in[7];
  const float* tb    = (const float*)d_in[8];
  float* out = (float*)d_out;

  // workspace layout (floats/ints, 4B units)
  float* xp  = (float*)d_ws;                       // 64000*128
  float* h1  = xp + (size_t)NNODE * 128;           // 64000*128
  float* h2  = h1 + (size_t)NNODE * 128;           // 64000*128
  float* deg = h2 + (size_t)NNODE * 128;           // 2000
  int*   cnt    = (int*)(deg + B_N);               // 2000
  int*   cursor = cnt + B_N;                       // 2000
  int*   offs   = cursor + B_N;                    // 2001
  int*   csr_src = offs + (B_N + 1);               // 32000
  float* csr_norm = (float*)(csr_src + E_N);       // 32000
  float* wT = csr_norm + E_N;                      // 96*128 = 12288

  // zero deg + cnt + cursor (contiguous 3*2000*4 bytes)
  hipMemsetAsync(deg, 0, (size_t)3 * B_N * 4, stream);

  k_wt<<<(96 * 128 + 255) / 256, 256, 0, stream>>>(cw, wT);
  k_conv_ln<<<B_N, 256, 0, stream>>>(x, wT, cb, gamma, beta, xp);
  k_deg<<<(E_N + 255) / 256, 256, 0, stream>>>(ei, ew, deg, cnt);
  k_scan<<<1, 256, 0, stream>>>(cnt, offs);
  k_scatter<<<(E_N + 255) / 256, 256, 0, stream>>>(ei, ew, deg, offs, cursor, csr_src, csr_norm);
  k_prop<<<NNODE / 4, 256, 0, stream>>>(xp, h1, offs, csr_src, csr_norm);
  k_prop<<<NNODE / 4, 256, 0, stream>>>(h1, h2, offs, csr_src, csr_norm);
  k_gemm<<<NNODE / 32, 256, 0, stream>>>(xp, h1, h2, tw, tb);
  k_out<<<B_N, 256, 0, stream>>>(h2, out);
}

// Round 3
// 314.278 us; speedup vs baseline: 1.5880x; 1.2246x over previous
//
#include <hip/hip_runtime.h>
#include <hip/hip_bf16.h>
#include <math.h>

#define B_N   2000
#define T_N   32
#define CIN_N 32
#define COUT_N 128
#define E_N   32000
#define NEG_S 0.01f
#define EPS_S 1e-5f
#define NNODE (B_N * T_N)   // 64000

typedef __attribute__((ext_vector_type(8))) __bf16 bf16x8;
typedef __attribute__((ext_vector_type(4))) float f32x4;

__device__ __forceinline__ unsigned short f2bf(float f) {
  unsigned u = __builtin_bit_cast(unsigned, f);
  u += 0x7FFFu + ((u >> 16) & 1u);   // RNE (finite values)
  return (unsigned short)(u >> 16);
}
__device__ __forceinline__ float bf2f(unsigned short h) {
  unsigned u = ((unsigned)h) << 16;
  return __builtin_bit_cast(float, u);
}

// ---------------- Kernel 0a: transpose conv weights [128][96] -> [96][128] fp32 ----------------
__global__ void k_wt(const float* __restrict__ cw, float* __restrict__ wT)
{
  int idx = blockIdx.x * 256 + threadIdx.x;   // 12288 total
  if (idx >= 96 * 128) return;
  int co = idx / 96, k = idx - co * 96;
  wT[k * 128 + co] = cw[idx];
}

// ---------------- Kernel 0b: tag weights [3][128][128] -> bf16 [col j][concat K] ----------------
// wTt[j*384 + (k*128+i)] = tag_w[k][i][j]
__global__ void k_twt(const float* __restrict__ tw, unsigned short* __restrict__ wTt)
{
  int idx = blockIdx.x * 256 + threadIdx.x;   // 49152 total
  if (idx >= 128 * 384) return;
  int j = idx / 384, kk = idx - j * 384;
  int k = kk >> 7, i = kk & 127;
  wTt[idx] = f2bf(tw[k * 16384 + i * 128 + j]);
}

// ---------------- Kernel 1: causal conv1d (as GEMM) + bias + LeakyReLU + LayerNorm -> bf16 xcat ----------------
__global__ __launch_bounds__(256) void k_conv_ln(
    const float* __restrict__ x, const float* __restrict__ wT,
    const float* __restrict__ cb, const float* __restrict__ gamma,
    const float* __restrict__ beta, unsigned short* __restrict__ xcat)
{
  __shared__ float swT[96 * 128];   // [k][co]
  __shared__ float sxi[96 * 36];    // im2col [k][t]
  __shared__ float red1[4], red2[4], sstat[2];
  const int b = blockIdx.x;
  const int tid = threadIdx.x;

  #pragma unroll
  for (int i = 0; i < 12; ++i) {
    int idx = i * 256 + tid;
    ((float4*)swT)[idx] = ((const float4*)wT)[idx];
  }
  #pragma unroll
  for (int i = 0; i < 12; ++i) {
    int idx = i * 256 + tid;                 // 3072 = 96*32
    int k = idx >> 5, t = idx & 31;
    int ci = k / 3, kk = k - ci * 3;
    int tt = t - 2 + kk;
    sxi[k * 36 + t] = (tt >= 0) ? x[b * 1024 + ci * 32 + tt] : 0.f;
  }
  __syncthreads();

  const int tx = tid & 31, ty = tid >> 5;
  const int co0 = tx * 4;
  const int t0 = ty * 4;
  float acc[4][4] = {};

  #pragma unroll 4
  for (int k = 0; k < 96; ++k) {
    const float4 xv = *(const float4*)&sxi[k * 36 + t0];
    const float4 wv = *(const float4*)&swT[k * 128 + co0];
    const float xs[4] = {xv.x, xv.y, xv.z, xv.w};
    #pragma unroll
    for (int i = 0; i < 4; ++i) {
      acc[i][0] += xs[i] * wv.x;
      acc[i][1] += xs[i] * wv.y;
      acc[i][2] += xs[i] * wv.z;
      acc[i][3] += xs[i] * wv.w;
    }
  }

  const float4 bv = *(const float4*)&cb[co0];
  const float bs[4] = {bv.x, bv.y, bv.z, bv.w};
  float s1 = 0.f, s2 = 0.f;
  #pragma unroll
  for (int i = 0; i < 4; ++i)
    #pragma unroll
    for (int j = 0; j < 4; ++j) {
      float u = acc[i][j] + bs[j];
      u = (u >= 0.f) ? u : NEG_S * u;
      acc[i][j] = u;
      s1 += u; s2 += u * u;
    }

  const int lane = tid & 63, wid = tid >> 6;
  #pragma unroll
  for (int d = 32; d > 0; d >>= 1) {
    s1 += __shfl_down(s1, d);
    s2 += __shfl_down(s2, d);
  }
  if (lane == 0) { red1[wid] = s1; red2[wid] = s2; }
  __syncthreads();
  if (tid == 0) {
    float a = red1[0] + red1[1] + red1[2] + red1[3];
    float c = red2[0] + red2[1] + red2[2] + red2[3];
    float mu = a / 4096.f;
    float var = c / 4096.f - mu * mu;
    sstat[0] = mu;
    sstat[1] = rsqrtf(var + EPS_S);
  }
  __syncthreads();
  const float mu = sstat[0], rs = sstat[1];

  // normalize + affine, write bf16 node-major xcat[(t*B+b)*384 + co] (cols 0..127)
  #pragma unroll
  for (int i = 0; i < 4; ++i) {
    const int t = t0 + i;
    ushort4 o;
    float v0 = (acc[i][0] - mu) * rs * gamma[(co0 + 0) * 32 + t] + beta[(co0 + 0) * 32 + t];
    float v1 = (acc[i][1] - mu) * rs * gamma[(co0 + 1) * 32 + t] + beta[(co0 + 1) * 32 + t];
    float v2 = (acc[i][2] - mu) * rs * gamma[(co0 + 2) * 32 + t] + beta[(co0 + 2) * 32 + t];
    float v3 = (acc[i][3] - mu) * rs * gamma[(co0 + 3) * 32 + t] + beta[(co0 + 3) * 32 + t];
    o.x = f2bf(v0); o.y = f2bf(v1); o.z = f2bf(v2); o.w = f2bf(v3);
    *(ushort4*)&xcat[(size_t)(t * B_N + b) * 384 + co0] = o;
  }
}

// ---------------- Kernel 2: in-degree (weighted) + in-edge counts ----------------
__global__ void k_deg(const int* __restrict__ ei, const float* __restrict__ ew,
                      float* __restrict__ deg, int* __restrict__ cnt)
{
  int e = blockIdx.x * 256 + threadIdx.x;
  if (e >= E_N) return;
  int d = ei[E_N + e];
  atomicAdd(&deg[d], ew[e]);
  atomicAdd(&cnt[d], 1);
}

// ---------------- Kernel 3: single-block exclusive scan over 2000 counts ----------------
__global__ __launch_bounds__(256) void k_scan(const int* __restrict__ cnt, int* __restrict__ offs)
{
  __shared__ int wsum[4];
  int tid = threadIdx.x;
  int vals[8];
  int run = 0;
  #pragma unroll
  for (int i = 0; i < 8; ++i) {
    int idx = tid * 8 + i;
    vals[i] = run;
    int v = (idx < B_N) ? cnt[idx] : 0;
    run += v;
  }
  int lane = tid & 63, wid = tid >> 6;
  int xs = run;
  #pragma unroll
  for (int d = 1; d < 64; d <<= 1) {
    int y = __shfl_up(xs, d);
    if (lane >= d) xs += y;
  }
  if (lane == 63) wsum[wid] = xs;
  __syncthreads();
  int pre = 0;
  for (int w = 0; w < wid; ++w) pre += wsum[w];
  int excl = pre + xs - run;
  #pragma unroll
  for (int i = 0; i < 8; ++i) {
    int idx = tid * 8 + i;
    if (idx <= B_N) offs[idx] = excl + vals[i];
  }
}

// ---------------- Kernel 4: CSR scatter + edge norm ----------------
__global__ void k_scatter(const int* __restrict__ ei, const float* __restrict__ ew,
                          const float* __restrict__ deg, const int* __restrict__ offs,
                          int* __restrict__ cursor, int* __restrict__ csr_src,
                          float* __restrict__ csr_norm)
{
  int e = blockIdx.x * 256 + threadIdx.x;
  if (e >= E_N) return;
  int s = ei[e], d = ei[E_N + e];
  float ds_ = deg[s], dd = deg[d];
  float dis_s = (ds_ > 0.f) ? rsqrtf(fmaxf(ds_, 1e-12f)) : 0.f;
  float dis_d = (dd  > 0.f) ? rsqrtf(fmaxf(dd,  1e-12f)) : 0.f;
  float nrm = dis_s * ew[e] * dis_d;
  int pos = offs[d] + atomicAdd(&cursor[d], 1);
  csr_src[pos] = s;
  csr_norm[pos] = nrm;
}

// ---------------- Kernel 5: one-hop propagation bf16->bf16 within xcat columns ----------------
// 1 wave per (dst node, timestep). Reads cols [cin,cin+128), writes cols [cout_,cout_+128).
__global__ __launch_bounds__(256) void k_prop(
    unsigned short* xcat, int cin, int cout_,
    const int* __restrict__ offs, const int* __restrict__ csr_src,
    const float* __restrict__ csr_norm)
{
  int gw = (blockIdx.x * 256 + threadIdx.x) >> 6;
  int lane = threadIdx.x & 63;
  if (gw >= NNODE) return;
  int t = gw / B_N;
  int b = gw - t * B_N;
  int beg = offs[b], end = offs[b + 1];
  const unsigned short* base = xcat + (size_t)t * B_N * 384 + cin + lane * 2;
  float ax = 0.f, ay = 0.f;
  for (int i = beg; i < end; ++i) {
    int s = csr_src[i];
    float nm = csr_norm[i];
    ushort2 v = *(const ushort2*)(base + (size_t)s * 384);
    ax += nm * bf2f(v.x);
    ay += nm * bf2f(v.y);
  }
  ushort2 o; o.x = f2bf(ax); o.y = f2bf(ay);
  *(ushort2*)&xcat[(size_t)gw * 384 + cout_ + lane * 2] = o;
}

// ---------------- Kernel 6: MFMA triple-GEMM (K=384) + bias + LeakyReLU + residual ----------------
// One wave per 16 output rows; 8 col-frags of 16; no LDS, A/B straight from global.
__global__ __launch_bounds__(256) void k_gemm(
    const unsigned short* __restrict__ xcat, const unsigned short* __restrict__ wTt,
    const float* __restrict__ tb, float* __restrict__ outn)
{
  const int wid = (blockIdx.x * 256 + threadIdx.x) >> 6;
  const int lane = threadIdx.x & 63;
  const int m0 = wid * 16;
  const int r = lane & 15, q = lane >> 4;

  const bf16x8* arow = (const bf16x8*)(xcat + (size_t)(m0 + r) * 384 + q * 8);
  const bf16x8* brow = (const bf16x8*)(wTt + (size_t)r * 384 + q * 8);

  f32x4 acc[8] = {};
  #pragma unroll
  for (int ks = 0; ks < 12; ++ks) {
    bf16x8 a = arow[ks * 4];
    #pragma unroll
    for (int nf = 0; nf < 8; ++nf) {
      bf16x8 bf = brow[nf * 768 + ks * 4];   // col block nf*16: offset nf*16*384 elems = nf*768 vecs
      acc[nf] = __builtin_amdgcn_mfma_f32_16x16x32_bf16(a, bf, acc[nf], 0, 0, 0);
    }
  }

  #pragma unroll
  for (int nf = 0; nf < 8; ++nf) {
    const int col = nf * 16 + r;
    const float bias = tb[col];
    #pragma unroll
    for (int i = 0; i < 4; ++i) {
      const int row = m0 + q * 4 + i;
      float u = acc[nf][i] + bias;
      u = (u >= 0.f) ? u : NEG_S * u;
      float xv = bf2f(xcat[(size_t)row * 384 + col]);   // residual from xp (cols 0..127)
      outn[(size_t)row * 128 + col] = xv + u;
    }
  }
}

// ---------------- Kernel 7: transpose [t*B+b][c] -> [b][c][t] ----------------
__global__ __launch_bounds__(256) void k_out(const float* __restrict__ hfin, float* __restrict__ out)
{
  __shared__ float lds[32 * 129];
  const int b = blockIdx.x, tid = threadIdx.x;
  #pragma unroll
  for (int i = 0; i < 16; ++i) {
    int idx = i * 256 + tid;
    int t = idx >> 7, c = idx & 127;
    lds[t * 129 + c] = hfin[(size_t)(t * B_N + b) * 128 + c];
  }
  __syncthreads();
  #pragma unroll
  for (int i = 0; i < 16; ++i) {
    int idx = i * 256 + tid;
    int c = idx >> 5, t = idx & 31;
    out[(size_t)b * 4096 + c * 32 + t] = lds[t * 129 + c];
  }
}

extern "C" void kernel_launch(void* const* d_in, const int* in_sizes, int n_in,
                              void* d_out, int out_size, void* d_ws, size_t ws_size,
                              hipStream_t stream)
{
  const float* x     = (const float*)d_in[0];
  const int*   ei    = (const int*)d_in[1];
  const float* ew    = (const float*)d_in[2];
  const float* cw    = (const float*)d_in[3];
  const float* cb    = (const float*)d_in[4];
  const float* gamma = (const float*)d_in[5];
  const float* beta  = (const float*)d_in[6];
  const float* tw    = (const float*)d_in[7];
  const float* tb    = (const float*)d_in[8];
  float* out = (float*)d_out;

  // workspace layout
  float* outn = (float*)d_ws;                                // 64000*128 fp32 (32.77 MB)
  unsigned short* xcat = (unsigned short*)(outn + (size_t)NNODE * 128);  // 64000*384 bf16 (49.15 MB)
  float* deg = (float*)(xcat + (size_t)NNODE * 384);         // 2000
  int*   cnt    = (int*)(deg + B_N);                         // 2000
  int*   cursor = cnt + B_N;                                 // 2000
  int*   offs   = cursor + B_N;                              // 2001
  int*   csr_src = offs + (B_N + 1);                         // 32000
  float* csr_norm = (float*)(csr_src + E_N);                 // 32000
  float* wT = csr_norm + E_N;                                // 96*128 fp32
  unsigned short* wTt = (unsigned short*)(wT + 96 * 128);    // 128*384 bf16

  hipMemsetAsync(deg, 0, (size_t)3 * B_N * 4, stream);

  k_wt<<<(96 * 128 + 255) / 256, 256, 0, stream>>>(cw, wT);
  k_twt<<<(128 * 384 + 255) / 256, 256, 0, stream>>>(tw, wTt);
  k_conv_ln<<<B_N, 256, 0, stream>>>(x, wT, cb, gamma, beta, xcat);
  k_deg<<<(E_N + 255) / 256, 256, 0, stream>>>(ei, ew, deg, cnt);
  k_scan<<<1, 256, 0, stream>>>(cnt, offs);
  k_scatter<<<(E_N + 255) / 256, 256, 0, stream>>>(ei, ew, deg, offs, cursor, csr_src, csr_norm);
  k_prop<<<NNODE / 4, 256, 0, stream>>>(xcat, 0, 128, offs, csr_src, csr_norm);
  k_prop<<<NNODE / 4, 256, 0, stream>>>(xcat, 128, 256, offs, csr_src, csr_norm);
  k_gemm<<<NNODE / 16 / 4, 256, 0, stream>>>(xcat, wTt, tb, outn);
  k_out<<<B_N, 256, 0, stream>>>(outn, out);
}

// Round 4
// 223.701 us; speedup vs baseline: 2.2310x; 1.4049x over previous
//
#include <hip/hip_runtime.h>
#include <hip/hip_bf16.h>
#include <math.h>

#define B_N   2000
#define T_N   32
#define CIN_N 32
#define COUT_N 128
#define E_N   32000
#define NEG_S 0.01f
#define EPS_S 1e-5f
#define NNODE (B_N * T_N)   // 64000
#define EPAD_N 38016        // E_N + 3*B_N rounded up: padded CSR capacity

typedef __attribute__((ext_vector_type(8))) __bf16 bf16x8;
typedef __attribute__((ext_vector_type(4))) float f32x4;

__device__ __forceinline__ unsigned short f2bf(float f) {
  unsigned u = __builtin_bit_cast(unsigned, f);
  u += 0x7FFFu + ((u >> 16) & 1u);   // RNE (finite values)
  return (unsigned short)(u >> 16);
}
__device__ __forceinline__ float bf2f(unsigned short h) {
  unsigned u = ((unsigned)h) << 16;
  return __builtin_bit_cast(float, u);
}

// ---------------- Kernel 0a: transpose conv weights [128][96] -> [96][128] fp32 ----------------
__global__ void k_wt(const float* __restrict__ cw, float* __restrict__ wT)
{
  int idx = blockIdx.x * 256 + threadIdx.x;   // 12288 total
  if (idx >= 96 * 128) return;
  int co = idx / 96, k = idx - co * 96;
  wT[k * 128 + co] = cw[idx];
}

// ---------------- Kernel 0b: tag weights [3][128][128] -> bf16 [col j][concat K] ----------------
// wTt[j*384 + (k*128+i)] = tag_w[k][i][j]
__global__ void k_twt(const float* __restrict__ tw, unsigned short* __restrict__ wTt)
{
  int idx = blockIdx.x * 256 + threadIdx.x;   // 49152 total
  if (idx >= 128 * 384) return;
  int j = idx / 384, kk = idx - j * 384;
  int k = kk >> 7, i = kk & 127;
  wTt[idx] = f2bf(tw[k * 16384 + i * 128 + j]);
}

// ---------------- Kernel 1: causal conv1d (as GEMM) + bias + LeakyReLU + LayerNorm -> bf16 xcat ----------------
__global__ __launch_bounds__(256) void k_conv_ln(
    const float* __restrict__ x, const float* __restrict__ wT,
    const float* __restrict__ cb, const float* __restrict__ gamma,
    const float* __restrict__ beta, unsigned short* __restrict__ xcat)
{
  __shared__ float swT[96 * 128];   // [k][co]
  __shared__ float sxi[96 * 36];    // im2col [k][t]
  __shared__ float red1[4], red2[4], sstat[2];
  const int b = blockIdx.x;
  const int tid = threadIdx.x;

  #pragma unroll
  for (int i = 0; i < 12; ++i) {
    int idx = i * 256 + tid;
    ((float4*)swT)[idx] = ((const float4*)wT)[idx];
  }
  #pragma unroll
  for (int i = 0; i < 12; ++i) {
    int idx = i * 256 + tid;                 // 3072 = 96*32
    int k = idx >> 5, t = idx & 31;
    int ci = k / 3, kk = k - ci * 3;
    int tt = t - 2 + kk;
    sxi[k * 36 + t] = (tt >= 0) ? x[b * 1024 + ci * 32 + tt] : 0.f;
  }
  __syncthreads();

  const int tx = tid & 31, ty = tid >> 5;
  const int co0 = tx * 4;
  const int t0 = ty * 4;
  float acc[4][4] = {};

  #pragma unroll 4
  for (int k = 0; k < 96; ++k) {
    const float4 xv = *(const float4*)&sxi[k * 36 + t0];
    const float4 wv = *(const float4*)&swT[k * 128 + co0];
    const float xs[4] = {xv.x, xv.y, xv.z, xv.w};
    #pragma unroll
    for (int i = 0; i < 4; ++i) {
      acc[i][0] += xs[i] * wv.x;
      acc[i][1] += xs[i] * wv.y;
      acc[i][2] += xs[i] * wv.z;
      acc[i][3] += xs[i] * wv.w;
    }
  }

  const float4 bv = *(const float4*)&cb[co0];
  const float bs[4] = {bv.x, bv.y, bv.z, bv.w};
  float s1 = 0.f, s2 = 0.f;
  #pragma unroll
  for (int i = 0; i < 4; ++i)
    #pragma unroll
    for (int j = 0; j < 4; ++j) {
      float u = acc[i][j] + bs[j];
      u = (u >= 0.f) ? u : NEG_S * u;
      acc[i][j] = u;
      s1 += u; s2 += u * u;
    }

  const int lane = tid & 63, wid = tid >> 6;
  #pragma unroll
  for (int d = 32; d > 0; d >>= 1) {
    s1 += __shfl_down(s1, d);
    s2 += __shfl_down(s2, d);
  }
  if (lane == 0) { red1[wid] = s1; red2[wid] = s2; }
  __syncthreads();
  if (tid == 0) {
    float a = red1[0] + red1[1] + red1[2] + red1[3];
    float c = red2[0] + red2[1] + red2[2] + red2[3];
    float mu = a / 4096.f;
    float var = c / 4096.f - mu * mu;
    sstat[0] = mu;
    sstat[1] = rsqrtf(var + EPS_S);
  }
  __syncthreads();
  const float mu = sstat[0], rs = sstat[1];

  // normalize + affine, write bf16 node-major xcat[(t*B+b)*384 + co] (cols 0..127)
  #pragma unroll
  for (int i = 0; i < 4; ++i) {
    const int t = t0 + i;
    ushort4 o;
    float v0 = (acc[i][0] - mu) * rs * gamma[(co0 + 0) * 32 + t] + beta[(co0 + 0) * 32 + t];
    float v1 = (acc[i][1] - mu) * rs * gamma[(co0 + 1) * 32 + t] + beta[(co0 + 1) * 32 + t];
    float v2 = (acc[i][2] - mu) * rs * gamma[(co0 + 2) * 32 + t] + beta[(co0 + 2) * 32 + t];
    float v3 = (acc[i][3] - mu) * rs * gamma[(co0 + 3) * 32 + t] + beta[(co0 + 3) * 32 + t];
    o.x = f2bf(v0); o.y = f2bf(v1); o.z = f2bf(v2); o.w = f2bf(v3);
    *(ushort4*)&xcat[(size_t)(t * B_N + b) * 384 + co0] = o;
  }
}

// ---------------- Kernel 2: in-degree (weighted) + in-edge counts ----------------
__global__ void k_deg(const int* __restrict__ ei, const float* __restrict__ ew,
                      float* __restrict__ deg, int* __restrict__ cnt)
{
  int e = blockIdx.x * 256 + threadIdx.x;
  if (e >= E_N) return;
  int d = ei[E_N + e];
  atomicAdd(&deg[d], ew[e]);
  atomicAdd(&cnt[d], 1);
}

// ---------------- Kernel 3: single-block exclusive scan over 2000 PADDED counts ----------------
// Pads each node's segment to a multiple of 4 so k_prop can use aligned int4/float4 loads.
__global__ __launch_bounds__(256) void k_scan(const int* __restrict__ cnt, int* __restrict__ offs)
{
  __shared__ int wsum[4];
  int tid = threadIdx.x;
  int vals[8];
  int run = 0;
  #pragma unroll
  for (int i = 0; i < 8; ++i) {
    int idx = tid * 8 + i;
    vals[i] = run;
    int v = (idx < B_N) ? cnt[idx] : 0;
    v = (v + 3) & ~3;                       // pad to multiple of 4
    run += v;
  }
  int lane = tid & 63, wid = tid >> 6;
  int xs = run;
  #pragma unroll
  for (int d = 1; d < 64; d <<= 1) {
    int y = __shfl_up(xs, d);
    if (lane >= d) xs += y;
  }
  if (lane == 63) wsum[wid] = xs;
  __syncthreads();
  int pre = 0;
  for (int w = 0; w < wid; ++w) pre += wsum[w];
  int excl = pre + xs - run;
  #pragma unroll
  for (int i = 0; i < 8; ++i) {
    int idx = tid * 8 + i;
    if (idx <= B_N) offs[idx] = excl + vals[i];
  }
}

// ---------------- Kernel 4: CSR scatter + edge norm (pad slots stay {src=0, norm=0}) ----------------
__global__ void k_scatter(const int* __restrict__ ei, const float* __restrict__ ew,
                          const float* __restrict__ deg, const int* __restrict__ offs,
                          int* __restrict__ cursor, int* __restrict__ csr_src,
                          float* __restrict__ csr_norm)
{
  int e = blockIdx.x * 256 + threadIdx.x;
  if (e >= E_N) return;
  int s = ei[e], d = ei[E_N + e];
  float ds_ = deg[s], dd = deg[d];
  float dis_s = (ds_ > 0.f) ? rsqrtf(fmaxf(ds_, 1e-12f)) : 0.f;
  float dis_d = (dd  > 0.f) ? rsqrtf(fmaxf(dd,  1e-12f)) : 0.f;
  float nrm = dis_s * ew[e] * dis_d;
  int pos = offs[d] + atomicAdd(&cursor[d], 1);
  csr_src[pos] = s;
  csr_norm[pos] = nrm;
}

// ---------------- Kernel 5: one-hop propagation, 4-wide edge unroll for MLP ----------------
// 1 wave per (dst node, timestep). Reads cols [cin,cin+128), writes cols [cout_,cout_+128).
__global__ __launch_bounds__(256) void k_prop(
    unsigned short* xcat, int cin, int cout_,
    const int* __restrict__ offs, const int* __restrict__ csr_src,
    const float* __restrict__ csr_norm)
{
  int gw = (blockIdx.x * 256 + threadIdx.x) >> 6;
  int lane = threadIdx.x & 63;
  if (gw >= NNODE) return;
  int t = gw / B_N;
  int b = gw - t * B_N;
  int beg = offs[b], end = offs[b + 1];           // both multiples of 4
  const unsigned short* base = xcat + (size_t)t * B_N * 384 + cin + lane * 2;
  float ax0 = 0.f, ay0 = 0.f, ax1 = 0.f, ay1 = 0.f;
  float ax2 = 0.f, ay2 = 0.f, ax3 = 0.f, ay3 = 0.f;
  for (int i = beg; i < end; i += 4) {
    int4   s4 = *(const int4*)&csr_src[i];        // uniform scalar load
    float4 n4 = *(const float4*)&csr_norm[i];     // uniform scalar load
    ushort2 v0 = *(const ushort2*)(base + (size_t)s4.x * 384);
    ushort2 v1 = *(const ushort2*)(base + (size_t)s4.y * 384);
    ushort2 v2 = *(const ushort2*)(base + (size_t)s4.z * 384);
    ushort2 v3 = *(const ushort2*)(base + (size_t)s4.w * 384);
    ax0 += n4.x * bf2f(v0.x); ay0 += n4.x * bf2f(v0.y);
    ax1 += n4.y * bf2f(v1.x); ay1 += n4.y * bf2f(v1.y);
    ax2 += n4.z * bf2f(v2.x); ay2 += n4.z * bf2f(v2.y);
    ax3 += n4.w * bf2f(v3.x); ay3 += n4.w * bf2f(v3.y);
  }
  float ax = (ax0 + ax1) + (ax2 + ax3);
  float ay = (ay0 + ay1) + (ay2 + ay3);
  ushort2 o; o.x = f2bf(ax); o.y = f2bf(ay);
  *(ushort2*)&xcat[(size_t)gw * 384 + cout_ + lane * 2] = o;
}

// ---------------- Kernel 6: MFMA triple-GEMM (K=384) + bias + LeakyReLU + residual ----------------
__global__ __launch_bounds__(256) void k_gemm(
    const unsigned short* __restrict__ xcat, const unsigned short* __restrict__ wTt,
    const float* __restrict__ tb, float* __restrict__ outn)
{
  const int wid = (blockIdx.x * 256 + threadIdx.x) >> 6;
  const int lane = threadIdx.x & 63;
  const int m0 = wid * 16;
  const int r = lane & 15, q = lane >> 4;

  const bf16x8* arow = (const bf16x8*)(xcat + (size_t)(m0 + r) * 384 + q * 8);
  const bf16x8* brow = (const bf16x8*)(wTt + (size_t)r * 384 + q * 8);

  f32x4 acc[8] = {};
  #pragma unroll
  for (int ks = 0; ks < 12; ++ks) {
    bf16x8 a = arow[ks * 4];
    #pragma unroll
    for (int nf = 0; nf < 8; ++nf) {
      bf16x8 bf = brow[nf * 768 + ks * 4];
      acc[nf] = __builtin_amdgcn_mfma_f32_16x16x32_bf16(a, bf, acc[nf], 0, 0, 0);
    }
  }

  #pragma unroll
  for (int nf = 0; nf < 8; ++nf) {
    const int col = nf * 16 + r;
    const float bias = tb[col];
    #pragma unroll
    for (int i = 0; i < 4; ++i) {
      const int row = m0 + q * 4 + i;
      float u = acc[nf][i] + bias;
      u = (u >= 0.f) ? u : NEG_S * u;
      float xv = bf2f(xcat[(size_t)row * 384 + col]);
      outn[(size_t)row * 128 + col] = xv + u;
    }
  }
}

// ---------------- Kernel 7: transpose [t*B+b][c] -> [b][c][t] ----------------
__global__ __launch_bounds__(256) void k_out(const float* __restrict__ hfin, float* __restrict__ out)
{
  __shared__ float lds[32 * 129];
  const int b = blockIdx.x, tid = threadIdx.x;
  #pragma unroll
  for (int i = 0; i < 16; ++i) {
    int idx = i * 256 + tid;
    int t = idx >> 7, c = idx & 127;
    lds[t * 129 + c] = hfin[(size_t)(t * B_N + b) * 128 + c];
  }
  __syncthreads();
  #pragma unroll
  for (int i = 0; i < 16; ++i) {
    int idx = i * 256 + tid;
    int c = idx >> 5, t = idx & 31;
    out[(size_t)b * 4096 + c * 32 + t] = lds[t * 129 + c];
  }
}

extern "C" void kernel_launch(void* const* d_in, const int* in_sizes, int n_in,
                              void* d_out, int out_size, void* d_ws, size_t ws_size,
                              hipStream_t stream)
{
  const float* x     = (const float*)d_in[0];
  const int*   ei    = (const int*)d_in[1];
  const float* ew    = (const float*)d_in[2];
  const float* cw    = (const float*)d_in[3];
  const float* cb    = (const float*)d_in[4];
  const float* gamma = (const float*)d_in[5];
  const float* beta  = (const float*)d_in[6];
  const float* tw    = (const float*)d_in[7];
  const float* tb    = (const float*)d_in[8];
  float* out = (float*)d_out;

  // workspace layout
  float* outn = (float*)d_ws;                                             // 64000*128 fp32
  unsigned short* xcat = (unsigned short*)(outn + (size_t)NNODE * 128);   // 64000*384 bf16
  float* deg = (float*)(xcat + (size_t)NNODE * 384);                      // 2000
  int*   cnt    = (int*)(deg + B_N);                                      // 2000
  int*   cursor = cnt + B_N;                                              // 2000
  int*   offs   = cursor + B_N;                                           // 2001
  int*   csr_src = offs + (B_N + 1);                                      // EPAD_N
  float* csr_norm = (float*)(csr_src + EPAD_N);                           // EPAD_N (contiguous)
  float* wT = csr_norm + EPAD_N;                                          // 96*128 fp32
  unsigned short* wTt = (unsigned short*)(wT + 96 * 128);                 // 128*384 bf16

  hipMemsetAsync(deg, 0, (size_t)3 * B_N * 4, stream);                    // deg+cnt+cursor
  hipMemsetAsync(csr_src, 0, (size_t)EPAD_N * 8, stream);                 // csr_src+csr_norm

  k_wt<<<(96 * 128 + 255) / 256, 256, 0, stream>>>(cw, wT);
  k_twt<<<(128 * 384 + 255) / 256, 256, 0, stream>>>(tw, wTt);
  k_conv_ln<<<B_N, 256, 0, stream>>>(x, wT, cb, gamma, beta, xcat);
  k_deg<<<(E_N + 255) / 256, 256, 0, stream>>>(ei, ew, deg, cnt);
  k_scan<<<1, 256, 0, stream>>>(cnt, offs);
  k_scatter<<<(E_N + 255) / 256, 256, 0, stream>>>(ei, ew, deg, offs, cursor, csr_src, csr_norm);
  k_prop<<<NNODE / 4, 256, 0, stream>>>(xcat, 0, 128, offs, csr_src, csr_norm);
  k_prop<<<NNODE / 4, 256, 0, stream>>>(xcat, 128, 256, offs, csr_src, csr_norm);
  k_gemm<<<NNODE / 16 / 4, 256, 0, stream>>>(xcat, wTt, tb, outn);
  k_out<<<B_N, 256, 0, stream>>>(outn, out);
}